// Round 1
// baseline (897.835 us; speedup 1.0000x reference)
//
#include <hip/hip_runtime.h>

// ---------------------------------------------------------------------------
// Problem constants (B,T,D)=(4,8192,1024), TREE_DEPTH=10, NUM_NODES=1023.
// Only levels 8..0 do work (level 9 fully masked); leaves = mean-8 pooling of
// x[:, :4096, :] into nodes 511..1022.  Children of node n are contiguous
// (2n+1, 2n+2) -> each GEMM A-row is a contiguous 2048-float slice of states.
// ---------------------------------------------------------------------------

#define NODES 1023
#define DIM   1024
#define K2    2048

typedef short short8 __attribute__((ext_vector_type(8)));
typedef float floatx4 __attribute__((ext_vector_type(4)));

__device__ __forceinline__ unsigned short f2bf(float f) {
    unsigned u = __float_as_uint(f);
    unsigned r = ((u >> 16) & 1u) + 0x7fffu;
    return (unsigned short)((u + r) >> 16);
}

#define GLD16(g, l)                                                            \
    __builtin_amdgcn_global_load_lds(                                          \
        (const __attribute__((address_space(1))) void*)(g),                    \
        (__attribute__((address_space(3))) void*)(l), 16, 0, 0)

// --------------------------- W -> bf16 conversion ---------------------------
__global__ __launch_bounds__(256) void k_cvt_w(const float* __restrict__ W,
                                               unsigned short* __restrict__ Wb) {
    int i = (blockIdx.x * 256 + threadIdx.x) * 4;
    float4 v = *(const float4*)(W + i);
    ushort4 o;
    o.x = f2bf(v.x); o.y = f2bf(v.y); o.z = f2bf(v.z); o.w = f2bf(v.w);
    *(ushort4*)(Wb + i) = o;
}

// --------------------------------- leaves -----------------------------------
// block = (leaf 0..511, b 0..3); 256 threads x float4
__global__ __launch_bounds__(256) void k_leaves(const float* __restrict__ x,
                                                float* __restrict__ Sf,
                                                unsigned short* __restrict__ Sb) {
    int leaf = blockIdx.x;
    int b = blockIdx.y;
    int d = threadIdx.x * 4;
    const float* xp = x + ((size_t)b * 8192 + (size_t)leaf * 8) * DIM + d;
    float4 s = {0.f, 0.f, 0.f, 0.f};
#pragma unroll
    for (int i = 0; i < 8; ++i) {
        float4 v = *(const float4*)(xp + (size_t)i * DIM);
        s.x += v.x; s.y += v.y; s.z += v.z; s.w += v.w;
    }
    s.x *= 0.125f; s.y *= 0.125f; s.z *= 0.125f; s.w *= 0.125f;
    size_t o = ((size_t)b * NODES + 511 + leaf) * DIM + d;
    *(float4*)(Sf + o) = s;
    ushort4 ob; ob.x = f2bf(s.x); ob.y = f2bf(s.y); ob.z = f2bf(s.z); ob.w = f2bf(s.w);
    *(ushort4*)(Sb + o) = ob;
}

// --------------------------- MFMA level (L >= 4) -----------------------------
// GEMM: R = 4<<L rows, K=2048, N=1024.  A row r: batch b=r>>L, local n=r&(2^L-1),
// base = Sb[b][child_start + 2n][0..2047] (contiguous).  B = Wb (1024x2048, NT).
// 128x128 tile, BK=64, 4 waves of 64x64, 16x16x32 bf16 MFMA.
__global__ __launch_bounds__(256) void k_level_mfma(
    const unsigned short* __restrict__ SbIn, const unsigned short* __restrict__ Wb,
    const float* __restrict__ bt, float* __restrict__ Sf,
    unsigned short* __restrict__ SbOut, int L, int R) {
    const int lvl_start = (1 << L) - 1;
    const int child_start = (2 << L) - 1;
    const int mask = (1 << L) - 1;

    __shared__ unsigned short Al[128 * 64];
    __shared__ unsigned short Bl[128 * 64];

    const int t = threadIdx.x;
    const int lane = t & 63;
    const int w = t >> 6;
    const int wm = w >> 1, wn = w & 1;
    const int bm = blockIdx.y, bn = blockIdx.x;

    floatx4 acc[4][4];
#pragma unroll
    for (int i = 0; i < 4; ++i)
#pragma unroll
        for (int j = 0; j < 4; ++j) acc[i][j] = (floatx4){0.f, 0.f, 0.f, 0.f};

    const int trow = t >> 3;          // 0..31
    const int tcol = (t & 7) * 8;     // element col within 64-wide K tile

    for (int k0 = 0; k0 < K2; k0 += 64) {
        // ---- stage A (128 x 64 bf16) ----
#pragma unroll
        for (int p = 0; p < 4; ++p) {
            int rg = bm * 128 + p * 32 + trow;
            rg = rg < R ? rg : R - 1;
            int bb = rg >> L;
            int nl = rg & mask;
            const unsigned short* g =
                SbIn + ((size_t)bb * NODES + child_start + 2 * nl) * DIM + k0 + tcol;
            GLD16(g, &Al[(p * 32 + w * 8) * 64]);
        }
        // ---- stage B (128 x 64 bf16) ----
#pragma unroll
        for (int p = 0; p < 4; ++p) {
            int rg = bn * 128 + p * 32 + trow;
            const unsigned short* g = Wb + (size_t)rg * K2 + k0 + tcol;
            GLD16(g, &Bl[(p * 32 + w * 8) * 64]);
        }
        __syncthreads();
        // ---- compute: two K=32 steps ----
#pragma unroll
        for (int ks = 0; ks < 2; ++ks) {
            short8 af[4], bf[4];
#pragma unroll
            for (int i = 0; i < 4; ++i) {
                af[i] = *(const short8*)&Al[(wm * 64 + i * 16 + (lane & 15)) * 64 +
                                            ks * 32 + (lane >> 4) * 8];
                bf[i] = *(const short8*)&Bl[(wn * 64 + i * 16 + (lane & 15)) * 64 +
                                            ks * 32 + (lane >> 4) * 8];
            }
#pragma unroll
            for (int i = 0; i < 4; ++i)
#pragma unroll
                for (int j = 0; j < 4; ++j)
                    acc[i][j] = __builtin_amdgcn_mfma_f32_16x16x32_bf16(
                        af[i], bf[j], acc[i][j], 0, 0, 0);
        }
        __syncthreads();
    }

    // ---- epilogue: gate by bt[L], write fp32 + bf16 states ----
#pragma unroll
    for (int i = 0; i < 4; ++i)
#pragma unroll
        for (int j = 0; j < 4; ++j)
#pragma unroll
            for (int r = 0; r < 4; ++r) {
                int m = bm * 128 + wm * 64 + i * 16 + (lane >> 4) * 4 + r;
                int n = bn * 128 + wn * 64 + j * 16 + (lane & 15);
                if (m < R) {
                    float v = acc[i][j][r];
                    float u = v - bt[L * DIM + n];
                    float o = (u > 0.f) ? v : 0.f;
                    int bb = m >> L;
                    int nl = m & mask;
                    size_t idx = ((size_t)bb * NODES + lvl_start + nl) * DIM + n;
                    Sf[idx] = o;
                    SbOut[idx] = f2bf(o);
                }
            }
}

// ------------------------- small level (L <= 3), fp32 ------------------------
// grid = (16 d-tiles, R rows); block 256 = 64 d x 4 k-chunks of 512.
__global__ __launch_bounds__(256) void k_level_small(
    const float* __restrict__ SfIn, const float* __restrict__ W,
    const float* __restrict__ bt, float* __restrict__ Sf,
    unsigned short* __restrict__ Sb, int L) {
    int r = blockIdx.y;
    int b = r >> L;
    int nl = r & ((1 << L) - 1);
    int node = (1 << L) - 1 + nl;
    int child = 2 * node + 1;
    const float* A = SfIn + ((size_t)b * NODES + child) * DIM;  // 2048 floats

    __shared__ float Alds[K2];
    int t = threadIdx.x;
    ((float4*)Alds)[t * 2] = ((const float4*)A)[t * 2];
    ((float4*)Alds)[t * 2 + 1] = ((const float4*)A)[t * 2 + 1];
    __syncthreads();

    int d = blockIdx.x * 64 + (t & 63);
    int kc = t >> 6;
    const float4* Wr = (const float4*)(W + (size_t)d * K2 + kc * 512);
    const float4* Ar = (const float4*)(Alds + kc * 512);
    float s = 0.f;
#pragma unroll 8
    for (int i = 0; i < 128; ++i) {
        float4 wv = Wr[i], av = Ar[i];
        s += wv.x * av.x + wv.y * av.y + wv.z * av.z + wv.w * av.w;
    }
    __shared__ float part[256];
    part[t] = s;
    __syncthreads();
    if (t < 64) {
        float v = part[t] + part[t + 64] + part[t + 128] + part[t + 192];
        float u = v - bt[L * DIM + d];
        float o = (u > 0.f) ? v : 0.f;
        size_t idx = ((size_t)b * NODES + node) * DIM + d;
        Sf[idx] = o;
        Sb[idx] = f2bf(o);
    }
}

// ------------------------- softmax over nodes + mixture ----------------------
__global__ __launch_bounds__(256) void k_mixture(const float* __restrict__ nw,
                                                 const float* __restrict__ Sf,
                                                 float* __restrict__ mix) {
    int d = blockIdx.x * 256 + threadIdx.x;  // 0..1023
    float denom = 0.f, n0 = 0.f, n1 = 0.f, n2 = 0.f, n3 = 0.f;
    for (int n = 0; n < NODES; ++n) {
        float wv = __expf(nw[(size_t)n * DIM + d]);
        denom += wv;
        n0 += wv * Sf[((size_t)0 * NODES + n) * DIM + d];
        n1 += wv * Sf[((size_t)1 * NODES + n) * DIM + d];
        n2 += wv * Sf[((size_t)2 * NODES + n) * DIM + d];
        n3 += wv * Sf[((size_t)3 * NODES + n) * DIM + d];
    }
    float inv = 1.f / denom;
    mix[0 * DIM + d] = n0 * inv;
    mix[1 * DIM + d] = n1 * inv;
    mix[2 * DIM + d] = n2 * inv;
    mix[3 * DIM + d] = n3 * inv;
}

// --------------------- out = rmsnorm(x + mixture) * rms_w --------------------
__global__ __launch_bounds__(256) void k_final(const float* __restrict__ x,
                                               const float* __restrict__ mix,
                                               const float* __restrict__ rw,
                                               float* __restrict__ out) {
    int row = blockIdx.x;       // b*8192 + t
    int b = row >> 13;
    size_t base = (size_t)row * DIM;
    int t = threadIdx.x;
    float4 xv = *(const float4*)(x + base + t * 4);
    float4 mv = *(const float4*)(mix + b * DIM + t * 4);
    float4 v = {xv.x + mv.x, xv.y + mv.y, xv.z + mv.z, xv.w + mv.w};
    float ss = v.x * v.x + v.y * v.y + v.z * v.z + v.w * v.w;
#pragma unroll
    for (int o = 32; o > 0; o >>= 1) ss += __shfl_xor(ss, o, 64);
    __shared__ float wsum[4];
    int lane = t & 63, wv_ = t >> 6;
    if (lane == 0) wsum[wv_] = ss;
    __syncthreads();
    float tot = wsum[0] + wsum[1] + wsum[2] + wsum[3];
    float inv = 1.f / sqrtf(tot * (1.f / 1024.f) + 1.1920929e-7f);
    float4 rwv = *(const float4*)(rw + t * 4);
    float4 o4 = {v.x * inv * rwv.x, v.y * inv * rwv.y, v.z * inv * rwv.z,
                 v.w * inv * rwv.w};
    *(float4*)(out + base + t * 4) = o4;
}

// ----------------------------------------------------------------------------
extern "C" void kernel_launch(void* const* d_in, const int* in_sizes, int n_in,
                              void* d_out, int out_size, void* d_ws, size_t ws_size,
                              hipStream_t stream) {
    (void)in_sizes; (void)n_in; (void)out_size; (void)ws_size;
    const float* x  = (const float*)d_in[0];
    const float* W  = (const float*)d_in[1];
    const float* nw = (const float*)d_in[2];
    const float* bt = (const float*)d_in[3];
    // d_in[4] = as_w, multiplied by 0.0 in reference -> unused
    const float* rw = (const float*)d_in[5];
    float* out = (float*)d_out;

    char* ws = (char*)d_ws;
    const size_t SF_BYTES = (size_t)4 * NODES * DIM * 4;   // 16,760,832
    const size_t SB_BYTES = (size_t)4 * NODES * DIM * 2;   //  8,380,416
    const size_t WB_BYTES = (size_t)K2 * DIM * 2;          //  4,194,304
    float* Sf = (float*)ws;
    unsigned short* Sb = (unsigned short*)(ws + SF_BYTES);
    unsigned short* Wb = (unsigned short*)(ws + SF_BYTES + SB_BYTES);
    float* mix = (float*)(ws + SF_BYTES + SB_BYTES + WB_BYTES);

    k_cvt_w<<<2048, 256, 0, stream>>>(W, Wb);
    k_leaves<<<dim3(512, 4), 256, 0, stream>>>(x, Sf, Sb);

    for (int L = 8; L >= 4; --L) {
        int R = 4 << L;
        dim3 grid(8, (R + 127) / 128);
        k_level_mfma<<<grid, 256, 0, stream>>>(Sb, Wb, bt, Sf, Sb, L, R);
    }
    for (int L = 3; L >= 0; --L) {
        int R = 4 << L;
        k_level_small<<<dim3(16, R), 256, 0, stream>>>(Sf, W, bt, Sf, Sb, L);
    }
    k_mixture<<<4, 256, 0, stream>>>(nw, Sf, mix);
    k_final<<<32768, 256, 0, stream>>>(x, mix, rw, out);
}

// Round 2
// 598.571 us; speedup vs baseline: 1.5000x; 1.5000x over previous
//
#include <hip/hip_runtime.h>

// ---------------------------------------------------------------------------
// Problem constants (B,T,D)=(4,8192,1024), TREE_DEPTH=10, NUM_NODES=1023.
// Only levels 8..0 do work (level 9 fully masked); leaves = mean-8 pooling of
// x[:, :4096, :] into nodes 511..1022.  Children of node n are contiguous
// (2n+1, 2n+2) -> each GEMM A-row is a contiguous 2048-float slice of states.
// ---------------------------------------------------------------------------

#define NODES 1023
#define DIM   1024
#define K2    2048
#define NCHUNK 64          // node chunks for mixture phase A (16 nodes each)

typedef short short8 __attribute__((ext_vector_type(8)));
typedef float floatx4 __attribute__((ext_vector_type(4)));

__device__ __forceinline__ unsigned short f2bf(float f) {
    unsigned u = __float_as_uint(f);
    unsigned r = ((u >> 16) & 1u) + 0x7fffu;
    return (unsigned short)((u + r) >> 16);
}

#define GLD16(g, l)                                                            \
    __builtin_amdgcn_global_load_lds(                                          \
        (const __attribute__((address_space(1))) void*)(g),                    \
        (__attribute__((address_space(3))) void*)(l), 16, 0, 0)

// --------------------------- W -> bf16 conversion ---------------------------
__global__ __launch_bounds__(256) void k_cvt_w(const float* __restrict__ W,
                                               unsigned short* __restrict__ Wb) {
    int i = (blockIdx.x * 256 + threadIdx.x) * 4;
    float4 v = *(const float4*)(W + i);
    ushort4 o;
    o.x = f2bf(v.x); o.y = f2bf(v.y); o.z = f2bf(v.z); o.w = f2bf(v.w);
    *(ushort4*)(Wb + i) = o;
}

// --------------------------------- leaves -----------------------------------
// block = (leaf 0..511, b 0..3); 256 threads x float4
__global__ __launch_bounds__(256) void k_leaves(const float* __restrict__ x,
                                                float* __restrict__ Sf,
                                                unsigned short* __restrict__ Sb) {
    int leaf = blockIdx.x;
    int b = blockIdx.y;
    int d = threadIdx.x * 4;
    const float* xp = x + ((size_t)b * 8192 + (size_t)leaf * 8) * DIM + d;
    float4 s = {0.f, 0.f, 0.f, 0.f};
#pragma unroll
    for (int i = 0; i < 8; ++i) {
        float4 v = *(const float4*)(xp + (size_t)i * DIM);
        s.x += v.x; s.y += v.y; s.z += v.z; s.w += v.w;
    }
    s.x *= 0.125f; s.y *= 0.125f; s.z *= 0.125f; s.w *= 0.125f;
    size_t o = ((size_t)b * NODES + 511 + leaf) * DIM + d;
    *(float4*)(Sf + o) = s;
    ushort4 ob; ob.x = f2bf(s.x); ob.y = f2bf(s.y); ob.z = f2bf(s.z); ob.w = f2bf(s.w);
    *(ushort4*)(Sb + o) = ob;
}

// --------------------------- MFMA level (L >= 4) -----------------------------
// GEMM: R = 4<<L rows, K=2048, N=1024.  A row r: batch b=r>>L, local n=r&(2^L-1),
// base = Sb[b][child_start + 2n][0..2047] (contiguous).  B = Wb (1024x2048, NT).
// 128x128 tile, BK=64, 4 waves of 64x64, 16x16x32 bf16 MFMA.
__global__ __launch_bounds__(256) void k_level_mfma(
    const unsigned short* __restrict__ SbIn, const unsigned short* __restrict__ Wb,
    const float* __restrict__ bt, float* __restrict__ Sf,
    unsigned short* __restrict__ SbOut, int L, int R) {
    const int lvl_start = (1 << L) - 1;
    const int child_start = (2 << L) - 1;
    const int mask = (1 << L) - 1;

    __shared__ unsigned short Al[128 * 64];
    __shared__ unsigned short Bl[128 * 64];

    const int t = threadIdx.x;
    const int lane = t & 63;
    const int w = t >> 6;
    const int wm = w >> 1, wn = w & 1;
    const int bm = blockIdx.y, bn = blockIdx.x;

    floatx4 acc[4][4];
#pragma unroll
    for (int i = 0; i < 4; ++i)
#pragma unroll
        for (int j = 0; j < 4; ++j) acc[i][j] = (floatx4){0.f, 0.f, 0.f, 0.f};

    const int trow = t >> 3;          // 0..31
    const int tcol = (t & 7) * 8;     // element col within 64-wide K tile

    for (int k0 = 0; k0 < K2; k0 += 64) {
        // ---- stage A (128 x 64 bf16) ----
#pragma unroll
        for (int p = 0; p < 4; ++p) {
            int rg = bm * 128 + p * 32 + trow;
            rg = rg < R ? rg : R - 1;
            int bb = rg >> L;
            int nl = rg & mask;
            const unsigned short* g =
                SbIn + ((size_t)bb * NODES + child_start + 2 * nl) * DIM + k0 + tcol;
            GLD16(g, &Al[(p * 32 + w * 8) * 64]);
        }
        // ---- stage B (128 x 64 bf16) ----
#pragma unroll
        for (int p = 0; p < 4; ++p) {
            int rg = bn * 128 + p * 32 + trow;
            const unsigned short* g = Wb + (size_t)rg * K2 + k0 + tcol;
            GLD16(g, &Bl[(p * 32 + w * 8) * 64]);
        }
        __syncthreads();
        // ---- compute: two K=32 steps ----
#pragma unroll
        for (int ks = 0; ks < 2; ++ks) {
            short8 af[4], bf[4];
#pragma unroll
            for (int i = 0; i < 4; ++i) {
                af[i] = *(const short8*)&Al[(wm * 64 + i * 16 + (lane & 15)) * 64 +
                                            ks * 32 + (lane >> 4) * 8];
                bf[i] = *(const short8*)&Bl[(wn * 64 + i * 16 + (lane & 15)) * 64 +
                                            ks * 32 + (lane >> 4) * 8];
            }
#pragma unroll
            for (int i = 0; i < 4; ++i)
#pragma unroll
                for (int j = 0; j < 4; ++j)
                    acc[i][j] = __builtin_amdgcn_mfma_f32_16x16x32_bf16(
                        af[i], bf[j], acc[i][j], 0, 0, 0);
        }
        __syncthreads();
    }

    // ---- epilogue: gate by bt[L], write fp32 + bf16 states ----
#pragma unroll
    for (int i = 0; i < 4; ++i)
#pragma unroll
        for (int j = 0; j < 4; ++j)
#pragma unroll
            for (int r = 0; r < 4; ++r) {
                int m = bm * 128 + wm * 64 + i * 16 + (lane >> 4) * 4 + r;
                int n = bn * 128 + wn * 64 + j * 16 + (lane & 15);
                if (m < R) {
                    float v = acc[i][j][r];
                    float u = v - bt[L * DIM + n];
                    float o = (u > 0.f) ? v : 0.f;
                    int bb = m >> L;
                    int nl = m & mask;
                    size_t idx = ((size_t)bb * NODES + lvl_start + nl) * DIM + n;
                    Sf[idx] = o;
                    SbOut[idx] = f2bf(o);
                }
            }
}

// ------------------------- small level (L <= 3), fp32 ------------------------
// grid = (16 d-tiles, R rows); block 256 = 64 d x 4 k-chunks of 512.
__global__ __launch_bounds__(256) void k_level_small(
    const float* __restrict__ SfIn, const float* __restrict__ W,
    const float* __restrict__ bt, float* __restrict__ Sf,
    unsigned short* __restrict__ Sb, int L) {
    int r = blockIdx.y;
    int b = r >> L;
    int nl = r & ((1 << L) - 1);
    int node = (1 << L) - 1 + nl;
    int child = 2 * node + 1;
    const float* A = SfIn + ((size_t)b * NODES + child) * DIM;  // 2048 floats

    __shared__ float Alds[K2];
    int t = threadIdx.x;
    ((float4*)Alds)[t * 2] = ((const float4*)A)[t * 2];
    ((float4*)Alds)[t * 2 + 1] = ((const float4*)A)[t * 2 + 1];
    __syncthreads();

    int d = blockIdx.x * 64 + (t & 63);
    int kc = t >> 6;
    const float4* Wr = (const float4*)(W + (size_t)d * K2 + kc * 512);
    const float4* Ar = (const float4*)(Alds + kc * 512);
    float s = 0.f;
#pragma unroll 8
    for (int i = 0; i < 128; ++i) {
        float4 wv = Wr[i], av = Ar[i];
        s += wv.x * av.x + wv.y * av.y + wv.z * av.z + wv.w * av.w;
    }
    __shared__ float part[256];
    part[t] = s;
    __syncthreads();
    if (t < 64) {
        float v = part[t] + part[t + 64] + part[t + 128] + part[t + 192];
        float u = v - bt[L * DIM + d];
        float o = (u > 0.f) ? v : 0.f;
        size_t idx = ((size_t)b * NODES + node) * DIM + d;
        Sf[idx] = o;
        Sb[idx] = f2bf(o);
    }
}

// ---------------- softmax mixture, phase A: partial sums per chunk -----------
// grid = (4 d-blocks, NCHUNK chunks); each chunk covers 16 nodes.
// part layout: part[(c*5 + j)*DIM + d], j=0 denom, j=1..4 batch numerators.
__global__ __launch_bounds__(256) void k_mixture_part(const float* __restrict__ nw,
                                                      const float* __restrict__ Sf,
                                                      float* __restrict__ part) {
    int d = blockIdx.x * 256 + threadIdx.x;  // 0..1023
    int c = blockIdx.y;
    int n0i = c * 16;
    int n1i = n0i + 16 < NODES ? n0i + 16 : NODES;
    float denom = 0.f, s0 = 0.f, s1 = 0.f, s2 = 0.f, s3 = 0.f;
    for (int n = n0i; n < n1i; ++n) {
        float wv = __expf(nw[(size_t)n * DIM + d]);
        denom += wv;
        s0 += wv * Sf[((size_t)0 * NODES + n) * DIM + d];
        s1 += wv * Sf[((size_t)1 * NODES + n) * DIM + d];
        s2 += wv * Sf[((size_t)2 * NODES + n) * DIM + d];
        s3 += wv * Sf[((size_t)3 * NODES + n) * DIM + d];
    }
    size_t base = ((size_t)c * 5) * DIM + d;
    part[base]           = denom;
    part[base + 1 * DIM] = s0;
    part[base + 2 * DIM] = s1;
    part[base + 3 * DIM] = s2;
    part[base + 4 * DIM] = s3;
}

// ---------------- softmax mixture, phase B: reduce chunks --------------------
__global__ __launch_bounds__(256) void k_mixture_red(const float* __restrict__ part,
                                                     float* __restrict__ mix) {
    int d = blockIdx.x * 256 + threadIdx.x;  // 0..1023
    float denom = 0.f, s0 = 0.f, s1 = 0.f, s2 = 0.f, s3 = 0.f;
#pragma unroll 8
    for (int c = 0; c < NCHUNK; ++c) {
        size_t base = ((size_t)c * 5) * DIM + d;
        denom += part[base];
        s0 += part[base + 1 * DIM];
        s1 += part[base + 2 * DIM];
        s2 += part[base + 3 * DIM];
        s3 += part[base + 4 * DIM];
    }
    float inv = 1.f / denom;
    mix[0 * DIM + d] = s0 * inv;
    mix[1 * DIM + d] = s1 * inv;
    mix[2 * DIM + d] = s2 * inv;
    mix[3 * DIM + d] = s3 * inv;
}

// --------------------- out = rmsnorm(x + mixture) * rms_w --------------------
__global__ __launch_bounds__(256) void k_final(const float* __restrict__ x,
                                               const float* __restrict__ mix,
                                               const float* __restrict__ rw,
                                               float* __restrict__ out) {
    int row = blockIdx.x;       // b*8192 + t
    int b = row >> 13;
    size_t base = (size_t)row * DIM;
    int t = threadIdx.x;
    float4 xv = *(const float4*)(x + base + t * 4);
    float4 mv = *(const float4*)(mix + b * DIM + t * 4);
    float4 v = {xv.x + mv.x, xv.y + mv.y, xv.z + mv.z, xv.w + mv.w};
    float ss = v.x * v.x + v.y * v.y + v.z * v.z + v.w * v.w;
#pragma unroll
    for (int o = 32; o > 0; o >>= 1) ss += __shfl_xor(ss, o, 64);
    __shared__ float wsum[4];
    int lane = t & 63, wv_ = t >> 6;
    if (lane == 0) wsum[wv_] = ss;
    __syncthreads();
    float tot = wsum[0] + wsum[1] + wsum[2] + wsum[3];
    float inv = 1.f / sqrtf(tot * (1.f / 1024.f) + 1.1920929e-7f);
    float4 rwv = *(const float4*)(rw + t * 4);
    float4 o4 = {v.x * inv * rwv.x, v.y * inv * rwv.y, v.z * inv * rwv.z,
                 v.w * inv * rwv.w};
    *(float4*)(out + base + t * 4) = o4;
}

// ----------------------------------------------------------------------------
extern "C" void kernel_launch(void* const* d_in, const int* in_sizes, int n_in,
                              void* d_out, int out_size, void* d_ws, size_t ws_size,
                              hipStream_t stream) {
    (void)in_sizes; (void)n_in; (void)out_size; (void)ws_size;
    const float* x  = (const float*)d_in[0];
    const float* W  = (const float*)d_in[1];
    const float* nw = (const float*)d_in[2];
    const float* bt = (const float*)d_in[3];
    // d_in[4] = as_w, multiplied by 0.0 in reference -> unused
    const float* rw = (const float*)d_in[5];
    float* out = (float*)d_out;

    char* ws = (char*)d_ws;
    const size_t SF_BYTES = (size_t)4 * NODES * DIM * 4;   // 16,760,832
    const size_t SB_BYTES = (size_t)4 * NODES * DIM * 2;   //  8,380,416
    const size_t WB_BYTES = (size_t)K2 * DIM * 2;          //  4,194,304
    const size_t MIX_BYTES = (size_t)4 * DIM * 4;          //     16,384
    float* Sf = (float*)ws;
    unsigned short* Sb = (unsigned short*)(ws + SF_BYTES);
    unsigned short* Wb = (unsigned short*)(ws + SF_BYTES + SB_BYTES);
    float* mix = (float*)(ws + SF_BYTES + SB_BYTES + WB_BYTES);
    float* part = (float*)(ws + SF_BYTES + SB_BYTES + WB_BYTES + MIX_BYTES);
    // part: NCHUNK * 5 * DIM floats = 1.31 MB

    k_cvt_w<<<2048, 256, 0, stream>>>(W, Wb);
    k_leaves<<<dim3(512, 4), 256, 0, stream>>>(x, Sf, Sb);

    for (int L = 8; L >= 4; --L) {
        int R = 4 << L;
        dim3 grid(8, (R + 127) / 128);
        k_level_mfma<<<grid, 256, 0, stream>>>(Sb, Wb, bt, Sf, Sb, L, R);
    }
    for (int L = 3; L >= 0; --L) {
        int R = 4 << L;
        k_level_small<<<dim3(16, R), 256, 0, stream>>>(Sf, W, bt, Sf, Sb, L);
    }
    k_mixture_part<<<dim3(4, NCHUNK), 256, 0, stream>>>(nw, Sf, part);
    k_mixture_red<<<4, 256, 0, stream>>>(part, mix);
    k_final<<<32768, 256, 0, stream>>>(x, mix, rw, out);
}